// Round 1
// baseline (10998.534 us; speedup 1.0000x reference)
//
#include <hip/hip_runtime.h>
#include <math.h>

#define N_USERS 100000
#define N_ITEMS 40000
#define N_NODES (N_USERS + N_ITEMS)
#define EMB 128
#define BATCH 8192
#define N_EDGES 1000000
#define N_LAYERS 3
#define ALPHA 0.1f
#define GAMMA 0.01f

// ---------------- init: cur = acc = concat(user_emb, item_emb) ----------------
__global__ void init_kernel(const float* __restrict__ user_emb,
                            const float* __restrict__ item_emb,
                            float* __restrict__ cur, float* __restrict__ acc) {
    const long long total4 = (long long)N_NODES * EMB / 4;
    const long long user4  = (long long)N_USERS * EMB / 4;
    long long i = (long long)blockIdx.x * blockDim.x + threadIdx.x;
    const long long stride = (long long)gridDim.x * blockDim.x;
    for (; i < total4; i += stride) {
        float4 v;
        if (i < user4) v = ((const float4*)user_emb)[i];
        else           v = ((const float4*)item_emb)[i - user4];
        ((float4*)cur)[i] = v;
        ((float4*)acc)[i] = v;
    }
}

// ---------------- SpMM: next[row] += val * cur[col]  (COO, atomic) ------------
// 32 lanes per edge, each lane handles 4 consecutive floats (float4 gather).
__global__ void spmm_kernel(const float* __restrict__ cur,
                            float* __restrict__ next,
                            const int* __restrict__ edge_user,
                            const int* __restrict__ edge_item,
                            const float* __restrict__ vals) {
    const int lane = threadIdx.x & 31;
    const long long g = (long long)blockIdx.x * (blockDim.x >> 5) + (threadIdx.x >> 5);
    const long long total = 2LL * N_EDGES;
    if (g >= total) return;
    int row, col;
    const float v = vals[g];
    if (g < N_EDGES) {
        row = edge_user[g];
        col = N_USERS + edge_item[g];
    } else {
        const long long e = g - N_EDGES;
        row = N_USERS + edge_item[e];
        col = edge_user[e];
    }
    const float4 x = ((const float4*)(cur + (long long)col * EMB))[lane];
    float* dst = next + (long long)row * EMB + lane * 4;
    atomicAdd(dst + 0, v * x.x);
    atomicAdd(dst + 1, v * x.y);
    atomicAdd(dst + 2, v * x.z);
    atomicAdd(dst + 3, v * x.w);
}

// ---------------- acc += next -------------------------------------------------
__global__ void accadd_kernel(float* __restrict__ acc, const float* __restrict__ nxt) {
    const long long total4 = (long long)N_NODES * EMB / 4;
    long long i = (long long)blockIdx.x * blockDim.x + threadIdx.x;
    const long long stride = (long long)gridDim.x * blockDim.x;
    for (; i < total4; i += stride) {
        float4 a = ((float4*)acc)[i];
        const float4 b = ((const float4*)nxt)[i];
        a.x += b.x; a.y += b.y; a.z += b.z; a.w += b.w;
        ((float4*)acc)[i] = a;
    }
}

__device__ inline float logsigmoidf(float x) {
    // log(sigmoid(x)), numerically stable
    return (x >= 0.f) ? -log1pf(expf(-x)) : (x - log1pf(expf(x)));
}

// ---------------- BCE + pred stats over [pos; neg] ---------------------------
// one 64-lane wave per pair; each lane covers 2 floats of the 128-dim dot.
// sums[0] += bce_term, sums[1] += pred, sums[2] += pred*log(pred)
__global__ void bce_kernel(const float* __restrict__ acc,
                           const int* __restrict__ users,
                           const int* __restrict__ pos_items,
                           const int* __restrict__ neg_items,
                           float* __restrict__ sums) {
    const int lane = threadIdx.x & 63;
    const long long w = (long long)blockIdx.x * (blockDim.x >> 6) + (threadIdx.x >> 6);
    if (w >= 2LL * BATCH) return;
    int u, it; float label;
    if (w < BATCH) { u = users[w];          it = pos_items[w];          label = 1.f; }
    else           { u = users[w - BATCH];  it = neg_items[w - BATCH];  label = 0.f; }
    const float2 a = ((const float2*)(acc + (long long)u * EMB))[lane];
    const float2 b = ((const float2*)(acc + (long long)(N_USERS + it) * EMB))[lane];
    float d = a.x * b.x + a.y * b.y;
    #pragma unroll
    for (int off = 32; off > 0; off >>= 1) d += __shfl_down(d, off);
    if (lane == 0) {
        d *= (1.f / 16.f);                // (acc/4)·(acc/4)
        const float ls  = logsigmoidf(d);   // log(pred)
        const float lsn = logsigmoidf(-d);  // log(1-pred)
        const float pred = 1.f / (1.f + expf(-d));
        const float bce = (label > 0.5f) ? -ls : -lsn;
        atomicAdd(&sums[0], bce);
        atomicAdd(&sums[1], pred);
        atomicAdd(&sums[2], pred * ls);
    }
}

// ---------------- sampled user/item preds ------------------------------------
// sums[3] += sigmoid(dot/16)
__global__ void ul_kernel(const float* __restrict__ acc,
                          const int* __restrict__ sampled_user,
                          const int* __restrict__ sampled_items,
                          float* __restrict__ sums) {
    const int lane = threadIdx.x & 63;
    const long long w = (long long)blockIdx.x * (blockDim.x >> 6) + (threadIdx.x >> 6);
    if (w >= 2LL * BATCH) return;
    const int u  = sampled_user[w];
    const int it = sampled_items[w];
    const float2 a = ((const float2*)(acc + (long long)u * EMB))[lane];
    const float2 b = ((const float2*)(acc + (long long)(N_USERS + it) * EMB))[lane];
    float d = a.x * b.x + a.y * b.y;
    #pragma unroll
    for (int off = 32; off > 0; off >>= 1) d += __shfl_down(d, off);
    if (lane == 0) {
        d *= (1.f / 16.f);
        const float pred = 1.f / (1.f + expf(-d));
        atomicAdd(&sums[3], pred);
    }
}

// ---------------- finalize ----------------------------------------------------
__global__ void finalize_kernel(const float* __restrict__ sums, float* __restrict__ out) {
    if (threadIdx.x == 0 && blockIdx.x == 0) {
        const float n = 2.f * BATCH;
        const float bce        = sums[0] / n;
        const float pred_avg   = sums[1] / n;
        const float plogp_avg  = sums[2] / n;
        const float predul_avg = sums[3] / n;
        const float info = ALPHA * (-pred_avg * logf(predul_avg)
                                    - (1.f - pred_avg) * logf(1.f - predul_avg))
                         + GAMMA * plogp_avg;
        out[0] = bce;
        out[1] = info;
    }
}

extern "C" void kernel_launch(void* const* d_in, const int* in_sizes, int n_in,
                              void* d_out, int out_size, void* d_ws, size_t ws_size,
                              hipStream_t stream) {
    const float* user_emb      = (const float*)d_in[0];
    const float* item_emb      = (const float*)d_in[1];
    const float* graph_vals    = (const float*)d_in[2];
    const int*   edge_user     = (const int*)d_in[3];
    const int*   edge_item     = (const int*)d_in[4];
    const int*   users         = (const int*)d_in[5];
    const int*   pos_items     = (const int*)d_in[6];
    const int*   neg_items     = (const int*)d_in[7];
    const int*   sampled_user  = (const int*)d_in[8];
    const int*   sampled_items = (const int*)d_in[9];
    float* out = (float*)d_out;

    const size_t embBytes = (size_t)N_NODES * EMB * sizeof(float);  // 71.68 MB
    char* ws = (char*)d_ws;
    float* bufA = (float*)(ws);
    float* bufB = (float*)(ws + embBytes);
    float* acc  = (float*)(ws + 2 * embBytes);
    float* sums = (float*)(ws + 3 * embBytes);

    hipMemsetAsync(sums, 0, 4 * sizeof(float), stream);
    init_kernel<<<2048, 256, 0, stream>>>(user_emb, item_emb, bufA, acc);

    float* cur = bufA;
    float* nxt = bufB;
    for (int l = 0; l < N_LAYERS; ++l) {
        hipMemsetAsync(nxt, 0, embBytes, stream);
        spmm_kernel<<<(2 * N_EDGES + 7) / 8, 256, 0, stream>>>(cur, nxt, edge_user,
                                                               edge_item, graph_vals);
        accadd_kernel<<<2048, 256, 0, stream>>>(acc, nxt);
        float* t = cur; cur = nxt; nxt = t;
    }

    bce_kernel<<<(2 * BATCH + 3) / 4, 256, 0, stream>>>(acc, users, pos_items,
                                                        neg_items, sums);
    ul_kernel<<<(2 * BATCH + 3) / 4, 256, 0, stream>>>(acc, sampled_user,
                                                       sampled_items, sums);
    finalize_kernel<<<1, 1, 0, stream>>>(sums, out);
}

// Round 2
// 1898.777 us; speedup vs baseline: 5.7924x; 5.7924x over previous
//
#include <hip/hip_runtime.h>
#include <math.h>

#define N_USERS 100000
#define N_ITEMS 40000
#define N_NODES (N_USERS + N_ITEMS)
#define EMB 128
#define BATCH 8192
#define N_EDGES 1000000
#define NNZ (2 * N_EDGES)
#define N_LAYERS 3
#define ALPHA 0.1f
#define GAMMA 0.01f

// ---------------- CSR build step 1: degree histogram --------------------------
__global__ void hist_kernel(const int* __restrict__ edge_user,
                            const int* __restrict__ edge_item,
                            int* __restrict__ deg) {
    int i = blockIdx.x * blockDim.x + threadIdx.x;
    const int stride = gridDim.x * blockDim.x;
    for (; i < NNZ; i += stride) {
        const int row = (i < N_EDGES) ? edge_user[i]
                                      : N_USERS + edge_item[i - N_EDGES];
        atomicAdd(&deg[row], 1);
    }
}

// ---------------- CSR build step 2: exclusive scan (single block) -------------
__global__ void scan_kernel(const int* __restrict__ deg,
                            int* __restrict__ row_start,
                            int* __restrict__ row_cur) {
    __shared__ int part[1024];
    const int t = threadIdx.x;
    const int chunk = (N_NODES + 1023) / 1024;
    const int beg = t * chunk;
    const int end = min(beg + chunk, N_NODES);
    int s = 0;
    for (int i = beg; i < end; ++i) s += deg[i];
    part[t] = s;
    __syncthreads();
    for (int off = 1; off < 1024; off <<= 1) {
        const int v = (t >= off) ? part[t - off] : 0;
        __syncthreads();
        part[t] += v;
        __syncthreads();
    }
    int prefix = (t == 0) ? 0 : part[t - 1];
    for (int i = beg; i < end; ++i) {
        row_start[i] = prefix;
        row_cur[i]   = prefix;
        prefix += deg[i];
    }
    if (t == 1023) row_start[N_NODES] = part[1023];
}

// ---------------- CSR build step 3: scatter edges -----------------------------
__global__ void scatter_kernel(const int* __restrict__ edge_user,
                               const int* __restrict__ edge_item,
                               const float* __restrict__ vals,
                               int* __restrict__ row_cur,
                               int* __restrict__ csr_col,
                               float* __restrict__ csr_val) {
    int i = blockIdx.x * blockDim.x + threadIdx.x;
    const int stride = gridDim.x * blockDim.x;
    for (; i < NNZ; i += stride) {
        int row, col;
        if (i < N_EDGES) { row = edge_user[i];            col = N_USERS + edge_item[i]; }
        else { const int e = i - N_EDGES; row = N_USERS + edge_item[e]; col = edge_user[e]; }
        const float v = vals[i];
        const int pos = atomicAdd(&row_cur[row], 1);
        csr_col[pos] = col;
        csr_val[pos] = v;
    }
}

// ---------------- init: cur = acc = concat(user_emb, item_emb) ----------------
__global__ void init_kernel(const float* __restrict__ user_emb,
                            const float* __restrict__ item_emb,
                            float* __restrict__ cur, float* __restrict__ acc) {
    const int total4 = N_NODES * EMB / 4;
    const int user4  = N_USERS * EMB / 4;
    int i = blockIdx.x * blockDim.x + threadIdx.x;
    const int stride = gridDim.x * blockDim.x;
    for (; i < total4; i += stride) {
        float4 v;
        if (i < user4) v = ((const float4*)user_emb)[i];
        else           v = ((const float4*)item_emb)[i - user4];
        ((float4*)cur)[i] = v;
        ((float4*)acc)[i] = v;
    }
}

// ---------------- SpMM (CSR, row-gather): nxt[r] = sum v*cur[c]; acc += nxt ---
// one 64-lane wave per row; float2 per lane covers EMB=128.
__global__ void spmm_csr_kernel(const float* __restrict__ cur,
                                float* __restrict__ nxt,
                                float* __restrict__ acc,
                                const int* __restrict__ row_start,
                                const int* __restrict__ csr_col,
                                const float* __restrict__ csr_val) {
    const int lane = threadIdx.x & 63;
    const int w = blockIdx.x * (blockDim.x >> 6) + (threadIdx.x >> 6);
    if (w >= N_NODES) return;
    const int beg = row_start[w];
    const int end = row_start[w + 1];
    float sx = 0.f, sy = 0.f;
    int j = beg;
    for (; j + 1 < end; j += 2) {
        const int   c0 = csr_col[j];
        const int   c1 = csr_col[j + 1];
        const float v0 = csr_val[j];
        const float v1 = csr_val[j + 1];
        const float2 x0 = ((const float2*)(cur + (size_t)c0 * EMB))[lane];
        const float2 x1 = ((const float2*)(cur + (size_t)c1 * EMB))[lane];
        sx = fmaf(v0, x0.x, sx); sy = fmaf(v0, x0.y, sy);
        sx = fmaf(v1, x1.x, sx); sy = fmaf(v1, x1.y, sy);
    }
    if (j < end) {
        const int   c0 = csr_col[j];
        const float v0 = csr_val[j];
        const float2 x0 = ((const float2*)(cur + (size_t)c0 * EMB))[lane];
        sx = fmaf(v0, x0.x, sx); sy = fmaf(v0, x0.y, sy);
    }
    float2* np = (float2*)(nxt + (size_t)w * EMB) + lane;
    float2* ap = (float2*)(acc + (size_t)w * EMB) + lane;
    np->x = sx; np->y = sy;
    float2 a = *ap;
    a.x += sx; a.y += sy;
    *ap = a;
}

__device__ inline float logsigmoidf(float x) {
    return (x >= 0.f) ? -log1pf(expf(-x)) : (x - log1pf(expf(x)));
}

// ---------------- BCE + pred stats over [pos; neg] ---------------------------
__global__ void bce_kernel(const float* __restrict__ acc,
                           const int* __restrict__ users,
                           const int* __restrict__ pos_items,
                           const int* __restrict__ neg_items,
                           float* __restrict__ sums) {
    const int lane = threadIdx.x & 63;
    const int w = blockIdx.x * (blockDim.x >> 6) + (threadIdx.x >> 6);
    if (w >= 2 * BATCH) return;
    int u, it; float label;
    if (w < BATCH) { u = users[w];         it = pos_items[w];         label = 1.f; }
    else           { u = users[w - BATCH]; it = neg_items[w - BATCH]; label = 0.f; }
    const float2 a = ((const float2*)(acc + (size_t)u * EMB))[lane];
    const float2 b = ((const float2*)(acc + (size_t)(N_USERS + it) * EMB))[lane];
    float d = a.x * b.x + a.y * b.y;
    #pragma unroll
    for (int off = 32; off > 0; off >>= 1) d += __shfl_down(d, off);
    if (lane == 0) {
        d *= (1.f / 16.f);                  // (acc/4)·(acc/4)
        const float ls   = logsigmoidf(d);  // log(pred)
        const float lsn  = logsigmoidf(-d); // log(1-pred)
        const float pred = 1.f / (1.f + expf(-d));
        const float bce  = (label > 0.5f) ? -ls : -lsn;
        atomicAdd(&sums[0], bce);
        atomicAdd(&sums[1], pred);
        atomicAdd(&sums[2], pred * ls);
    }
}

// ---------------- sampled user/item preds ------------------------------------
__global__ void ul_kernel(const float* __restrict__ acc,
                          const int* __restrict__ sampled_user,
                          const int* __restrict__ sampled_items,
                          float* __restrict__ sums) {
    const int lane = threadIdx.x & 63;
    const int w = blockIdx.x * (blockDim.x >> 6) + (threadIdx.x >> 6);
    if (w >= 2 * BATCH) return;
    const int u  = sampled_user[w];
    const int it = sampled_items[w];
    const float2 a = ((const float2*)(acc + (size_t)u * EMB))[lane];
    const float2 b = ((const float2*)(acc + (size_t)(N_USERS + it) * EMB))[lane];
    float d = a.x * b.x + a.y * b.y;
    #pragma unroll
    for (int off = 32; off > 0; off >>= 1) d += __shfl_down(d, off);
    if (lane == 0) {
        d *= (1.f / 16.f);
        const float pred = 1.f / (1.f + expf(-d));
        atomicAdd(&sums[3], pred);
    }
}

// ---------------- finalize ----------------------------------------------------
__global__ void finalize_kernel(const float* __restrict__ sums, float* __restrict__ out) {
    if (threadIdx.x == 0 && blockIdx.x == 0) {
        const float n = 2.f * BATCH;
        const float bce        = sums[0] / n;
        const float pred_avg   = sums[1] / n;
        const float plogp_avg  = sums[2] / n;
        const float predul_avg = sums[3] / n;
        const float info = ALPHA * (-pred_avg * logf(predul_avg)
                                    - (1.f - pred_avg) * logf(1.f - predul_avg))
                         + GAMMA * plogp_avg;
        out[0] = bce;
        out[1] = info;
    }
}

extern "C" void kernel_launch(void* const* d_in, const int* in_sizes, int n_in,
                              void* d_out, int out_size, void* d_ws, size_t ws_size,
                              hipStream_t stream) {
    const float* user_emb      = (const float*)d_in[0];
    const float* item_emb      = (const float*)d_in[1];
    const float* graph_vals    = (const float*)d_in[2];
    const int*   edge_user     = (const int*)d_in[3];
    const int*   edge_item     = (const int*)d_in[4];
    const int*   users         = (const int*)d_in[5];
    const int*   pos_items     = (const int*)d_in[6];
    const int*   neg_items     = (const int*)d_in[7];
    const int*   sampled_user  = (const int*)d_in[8];
    const int*   sampled_items = (const int*)d_in[9];
    float* out = (float*)d_out;

    const size_t embBytes = (size_t)N_NODES * EMB * sizeof(float);  // 71.68 MB
    char* ws = (char*)d_ws;
    size_t off = 0;
    float* bufA = (float*)(ws + off); off += embBytes;
    float* bufB = (float*)(ws + off); off += embBytes;
    float* acc  = (float*)(ws + off); off += embBytes;
    float* sums = (float*)(ws + off); off += 256;  // 4 floats, padded
    int*   deg       = (int*)(ws + off); off += (size_t)N_NODES * 4;
    int*   row_start = (int*)(ws + off); off += (size_t)(N_NODES + 1) * 4 + 252;
    int*   row_cur   = (int*)(ws + off); off += (size_t)N_NODES * 4;
    int*   csr_col   = (int*)(ws + off); off += (size_t)NNZ * 4;
    float* csr_val   = (float*)(ws + off); off += (size_t)NNZ * 4;

    hipMemsetAsync(deg, 0, (size_t)N_NODES * 4, stream);
    hipMemsetAsync(sums, 0, 4 * sizeof(float), stream);

    hist_kernel<<<2048, 256, 0, stream>>>(edge_user, edge_item, deg);
    scan_kernel<<<1, 1024, 0, stream>>>(deg, row_start, row_cur);
    scatter_kernel<<<2048, 256, 0, stream>>>(edge_user, edge_item, graph_vals,
                                             row_cur, csr_col, csr_val);
    init_kernel<<<2048, 256, 0, stream>>>(user_emb, item_emb, bufA, acc);

    float* cur = bufA;
    float* nxt = bufB;
    for (int l = 0; l < N_LAYERS; ++l) {
        spmm_csr_kernel<<<(N_NODES + 3) / 4, 256, 0, stream>>>(cur, nxt, acc,
                                                               row_start, csr_col, csr_val);
        float* t = cur; cur = nxt; nxt = t;
    }

    bce_kernel<<<(2 * BATCH + 3) / 4, 256, 0, stream>>>(acc, users, pos_items,
                                                        neg_items, sums);
    ul_kernel<<<(2 * BATCH + 3) / 4, 256, 0, stream>>>(acc, sampled_user,
                                                       sampled_items, sums);
    finalize_kernel<<<1, 1, 0, stream>>>(sums, out);
}

// Round 3
// 1084.715 us; speedup vs baseline: 10.1396x; 1.7505x over previous
//
#include <hip/hip_runtime.h>
#include <math.h>

#define N_USERS 100000
#define N_ITEMS 40000
#define N_NODES (N_USERS + N_ITEMS)
#define EMB 128
#define BATCH 8192
#define N_EDGES 1000000
#define NNZ (2 * N_EDGES)
#define N_LAYERS 3
#define ALPHA 0.1f
#define GAMMA 0.01f

// ---------------- CSR build step 1: degree histogram --------------------------
__global__ void hist_kernel(const int* __restrict__ edge_user,
                            const int* __restrict__ edge_item,
                            int* __restrict__ deg) {
    int i = blockIdx.x * blockDim.x + threadIdx.x;
    const int stride = gridDim.x * blockDim.x;
    for (; i < NNZ; i += stride) {
        const int row = (i < N_EDGES) ? edge_user[i]
                                      : N_USERS + edge_item[i - N_EDGES];
        atomicAdd(&deg[row], 1);
    }
}

// ---------------- CSR build step 2: exclusive scan (single block) -------------
__global__ void scan_kernel(const int* __restrict__ deg,
                            int* __restrict__ row_start,
                            int* __restrict__ row_cur) {
    __shared__ int part[1024];
    const int t = threadIdx.x;
    const int chunk = (N_NODES + 1023) / 1024;
    const int beg = t * chunk;
    const int end = min(beg + chunk, N_NODES);
    int s = 0;
    for (int i = beg; i < end; ++i) s += deg[i];
    part[t] = s;
    __syncthreads();
    for (int off = 1; off < 1024; off <<= 1) {
        const int v = (t >= off) ? part[t - off] : 0;
        __syncthreads();
        part[t] += v;
        __syncthreads();
    }
    int prefix = (t == 0) ? 0 : part[t - 1];
    for (int i = beg; i < end; ++i) {
        row_start[i] = prefix;
        row_cur[i]   = prefix;
        prefix += deg[i];
    }
    if (t == 1023) row_start[N_NODES] = part[1023];
}

// ---------------- CSR build step 3: scatter edges -----------------------------
__global__ void scatter_kernel(const int* __restrict__ edge_user,
                               const int* __restrict__ edge_item,
                               const float* __restrict__ vals,
                               int* __restrict__ row_cur,
                               int* __restrict__ csr_col,
                               float* __restrict__ csr_val) {
    int i = blockIdx.x * blockDim.x + threadIdx.x;
    const int stride = gridDim.x * blockDim.x;
    for (; i < NNZ; i += stride) {
        int row, col;
        if (i < N_EDGES) { row = edge_user[i];            col = N_USERS + edge_item[i]; }
        else { const int e = i - N_EDGES; row = N_USERS + edge_item[e]; col = edge_user[e]; }
        const float v = vals[i];
        const int pos = atomicAdd(&row_cur[row], 1);
        csr_col[pos] = col;
        csr_val[pos] = v;
    }
}

// ---------------- init: cur = acc = concat(user_emb, item_emb) ----------------
__global__ void init_kernel(const float* __restrict__ user_emb,
                            const float* __restrict__ item_emb,
                            float* __restrict__ cur, float* __restrict__ acc) {
    const int total4 = N_NODES * EMB / 4;
    const int user4  = N_USERS * EMB / 4;
    int i = blockIdx.x * blockDim.x + threadIdx.x;
    const int stride = gridDim.x * blockDim.x;
    for (; i < total4; i += stride) {
        float4 v;
        if (i < user4) v = ((const float4*)user_emb)[i];
        else           v = ((const float4*)item_emb)[i - user4];
        ((float4*)cur)[i] = v;
        ((float4*)acc)[i] = v;
    }
}

// ---------------- SpMM (CSR, row-gather): nxt[r] = sum v*cur[c]; acc += nxt ---
// one 64-lane wave per row; float2 per lane covers EMB=128.
__global__ void spmm_csr_kernel(const float* __restrict__ cur,
                                float* __restrict__ nxt,
                                float* __restrict__ acc,
                                const int* __restrict__ row_start,
                                const int* __restrict__ csr_col,
                                const float* __restrict__ csr_val) {
    const int lane = threadIdx.x & 63;
    const int w = blockIdx.x * (blockDim.x >> 6) + (threadIdx.x >> 6);
    if (w >= N_NODES) return;
    const int beg = row_start[w];
    const int end = row_start[w + 1];
    float sx = 0.f, sy = 0.f;
    int j = beg;
    for (; j + 1 < end; j += 2) {
        const int   c0 = csr_col[j];
        const int   c1 = csr_col[j + 1];
        const float v0 = csr_val[j];
        const float v1 = csr_val[j + 1];
        const float2 x0 = ((const float2*)(cur + (size_t)c0 * EMB))[lane];
        const float2 x1 = ((const float2*)(cur + (size_t)c1 * EMB))[lane];
        sx = fmaf(v0, x0.x, sx); sy = fmaf(v0, x0.y, sy);
        sx = fmaf(v1, x1.x, sx); sy = fmaf(v1, x1.y, sy);
    }
    if (j < end) {
        const int   c0 = csr_col[j];
        const float v0 = csr_val[j];
        const float2 x0 = ((const float2*)(cur + (size_t)c0 * EMB))[lane];
        sx = fmaf(v0, x0.x, sx); sy = fmaf(v0, x0.y, sy);
    }
    float2* np = (float2*)(nxt + (size_t)w * EMB) + lane;
    float2* ap = (float2*)(acc + (size_t)w * EMB) + lane;
    np->x = sx; np->y = sy;
    float2 a = *ap;
    a.x += sx; a.y += sy;
    *ap = a;
}

__device__ inline float logsigmoidf(float x) {
    return (x >= 0.f) ? -log1pf(expf(-x)) : (x - log1pf(expf(x)));
}

// ---------------- fused losses ------------------------------------------------
// Work items p in [0, 4*BATCH): p<BATCH pos, p<2B neg, else sampled (ul).
// Wave per pair, grid-stride; register accumulators; LDS block reduce;
// ONE atomicAdd per sum per block (kills same-address atomic serialization).
__global__ void loss_kernel(const float* __restrict__ acc,
                            const int* __restrict__ users,
                            const int* __restrict__ pos_items,
                            const int* __restrict__ neg_items,
                            const int* __restrict__ sampled_user,
                            const int* __restrict__ sampled_items,
                            float* __restrict__ sums) {
    const int lane = threadIdx.x & 63;
    const int wid  = threadIdx.x >> 6;            // 0..3
    const int gw   = blockIdx.x * 4 + wid;
    const int nw   = gridDim.x * 4;
    float s_bce = 0.f, s_pred = 0.f, s_plogp = 0.f, s_ul = 0.f;
    for (int p = gw; p < 4 * BATCH; p += nw) {
        int u, it;
        if (p < 2 * BATCH) {
            if (p < BATCH) { u = users[p];          it = pos_items[p]; }
            else           { u = users[p - BATCH];  it = neg_items[p - BATCH]; }
        } else {
            const int q = p - 2 * BATCH;
            u = sampled_user[q]; it = sampled_items[q];
        }
        const float2 a = ((const float2*)(acc + (size_t)u * EMB))[lane];
        const float2 b = ((const float2*)(acc + (size_t)(N_USERS + it) * EMB))[lane];
        float d = a.x * b.x + a.y * b.y;
        #pragma unroll
        for (int off = 32; off > 0; off >>= 1) d += __shfl_down(d, off);
        if (lane == 0) {
            d *= (1.f / 16.f);                  // (acc/4)·(acc/4)
            const float pred = 1.f / (1.f + expf(-d));
            if (p < 2 * BATCH) {
                const float ls  = logsigmoidf(d);
                const float lsn = logsigmoidf(-d);
                s_bce   += (p < BATCH) ? -ls : -lsn;
                s_pred  += pred;
                s_plogp += pred * ls;
            } else {
                s_ul += pred;
            }
        }
    }
    __shared__ float red[4][4];
    if (lane == 0) {
        red[wid][0] = s_bce; red[wid][1] = s_pred;
        red[wid][2] = s_plogp; red[wid][3] = s_ul;
    }
    __syncthreads();
    if (threadIdx.x < 4) {
        const float v = red[0][threadIdx.x] + red[1][threadIdx.x]
                      + red[2][threadIdx.x] + red[3][threadIdx.x];
        atomicAdd(&sums[threadIdx.x], v);
    }
}

// ---------------- finalize ----------------------------------------------------
__global__ void finalize_kernel(const float* __restrict__ sums, float* __restrict__ out) {
    if (threadIdx.x == 0 && blockIdx.x == 0) {
        const float n = 2.f * BATCH;
        const float bce        = sums[0] / n;
        const float pred_avg   = sums[1] / n;
        const float plogp_avg  = sums[2] / n;
        const float predul_avg = sums[3] / n;
        const float info = ALPHA * (-pred_avg * logf(predul_avg)
                                    - (1.f - pred_avg) * logf(1.f - predul_avg))
                         + GAMMA * plogp_avg;
        out[0] = bce;
        out[1] = info;
    }
}

extern "C" void kernel_launch(void* const* d_in, const int* in_sizes, int n_in,
                              void* d_out, int out_size, void* d_ws, size_t ws_size,
                              hipStream_t stream) {
    const float* user_emb      = (const float*)d_in[0];
    const float* item_emb      = (const float*)d_in[1];
    const float* graph_vals    = (const float*)d_in[2];
    const int*   edge_user     = (const int*)d_in[3];
    const int*   edge_item     = (const int*)d_in[4];
    const int*   users         = (const int*)d_in[5];
    const int*   pos_items     = (const int*)d_in[6];
    const int*   neg_items     = (const int*)d_in[7];
    const int*   sampled_user  = (const int*)d_in[8];
    const int*   sampled_items = (const int*)d_in[9];
    float* out = (float*)d_out;

    const size_t embBytes = (size_t)N_NODES * EMB * sizeof(float);  // 71.68 MB
    char* ws = (char*)d_ws;
    size_t off = 0;
    float* bufA = (float*)(ws + off); off += embBytes;
    float* bufB = (float*)(ws + off); off += embBytes;
    float* acc  = (float*)(ws + off); off += embBytes;
    float* sums = (float*)(ws + off); off += 256;  // 4 floats, padded
    int*   deg       = (int*)(ws + off); off += (size_t)N_NODES * 4;
    int*   row_start = (int*)(ws + off); off += (size_t)(N_NODES + 1) * 4 + 252;
    int*   row_cur   = (int*)(ws + off); off += (size_t)N_NODES * 4;
    int*   csr_col   = (int*)(ws + off); off += (size_t)NNZ * 4;
    float* csr_val   = (float*)(ws + off); off += (size_t)NNZ * 4;

    hipMemsetAsync(deg, 0, (size_t)N_NODES * 4, stream);
    hipMemsetAsync(sums, 0, 4 * sizeof(float), stream);

    hist_kernel<<<2048, 256, 0, stream>>>(edge_user, edge_item, deg);
    scan_kernel<<<1, 1024, 0, stream>>>(deg, row_start, row_cur);
    scatter_kernel<<<2048, 256, 0, stream>>>(edge_user, edge_item, graph_vals,
                                             row_cur, csr_col, csr_val);
    init_kernel<<<2048, 256, 0, stream>>>(user_emb, item_emb, bufA, acc);

    float* cur = bufA;
    float* nxt = bufB;
    for (int l = 0; l < N_LAYERS; ++l) {
        spmm_csr_kernel<<<(N_NODES + 3) / 4, 256, 0, stream>>>(cur, nxt, acc,
                                                               row_start, csr_col, csr_val);
        float* t = cur; cur = nxt; nxt = t;
    }

    loss_kernel<<<512, 256, 0, stream>>>(acc, users, pos_items, neg_items,
                                         sampled_user, sampled_items, sums);
    finalize_kernel<<<1, 1, 0, stream>>>(sums, out);
}

// Round 4
// 778.778 us; speedup vs baseline: 14.1228x; 1.3928x over previous
//
#include <hip/hip_runtime.h>
#include <math.h>

#define N_USERS 100000
#define N_ITEMS 40000
#define N_NODES (N_USERS + N_ITEMS)
#define EMB 128
#define BATCH 8192
#define N_EDGES 1000000
#define NNZ (2 * N_EDGES)
#define N_LAYERS 3
#define ALPHA 0.1f
#define GAMMA 0.01f

#define SCAN_BLOCKS 256
#define SCAN_CHUNK ((N_NODES + SCAN_BLOCKS - 1) / SCAN_BLOCKS)   /* 547 */
#define SCAN_PER_THREAD ((SCAN_CHUNK + 255) / 256)               /* 3 */

// ---------------- CSR build step 1: degree histogram --------------------------
__global__ void hist_kernel(const int* __restrict__ edge_user,
                            const int* __restrict__ edge_item,
                            int* __restrict__ deg) {
    int i = blockIdx.x * blockDim.x + threadIdx.x;
    const int stride = gridDim.x * blockDim.x;
    for (; i < NNZ; i += stride) {
        const int row = (i < N_EDGES) ? edge_user[i]
                                      : N_USERS + edge_item[i - N_EDGES];
        atomicAdd(&deg[row], 1);
    }
}

// ---------------- CSR scan phase 1: per-block chunk sums ----------------------
__global__ void partial_kernel(const int* __restrict__ deg, int* __restrict__ bsum) {
    const int b = blockIdx.x;
    const int t = threadIdx.x;
    const int base = b * SCAN_CHUNK + t * SCAN_PER_THREAD;
    const int lim = min((b + 1) * SCAN_CHUNK, N_NODES);
    int s = 0;
    #pragma unroll
    for (int k = 0; k < SCAN_PER_THREAD; ++k) {
        const int i = base + k;
        if (i < lim) s += deg[i];
    }
    __shared__ int red[4];
    #pragma unroll
    for (int off = 32; off > 0; off >>= 1) s += __shfl_down(s, off);
    const int lane = t & 63, wid = t >> 6;
    if (lane == 0) red[wid] = s;
    __syncthreads();
    if (t == 0) bsum[b] = red[0] + red[1] + red[2] + red[3];
}

// ---------------- CSR scan phase 2: scan 256 block sums (tiny) ----------------
__global__ void scanb_kernel(const int* __restrict__ bsum, int* __restrict__ boff,
                             int* __restrict__ row_start) {
    const int t = threadIdx.x;        // 256 threads
    const int lane = t & 63, wid = t >> 6;
    const int v = bsum[t];
    int x = v;
    #pragma unroll
    for (int off = 1; off < 64; off <<= 1) {
        const int y = __shfl_up(x, off);
        if (lane >= off) x += y;
    }
    __shared__ int wtot[4];
    if (lane == 63) wtot[wid] = x;
    __syncthreads();
    int wo = 0;
    for (int k = 0; k < wid; ++k) wo += wtot[k];
    boff[t] = wo + x - v;             // exclusive prefix of block t
    if (t == 255) row_start[N_NODES] = wo + x;   // == NNZ
}

// ---------------- CSR scan phase 3: emit row_start / row_cur ------------------
__global__ void emit_kernel(const int* __restrict__ deg, const int* __restrict__ boff,
                            int* __restrict__ row_start, int* __restrict__ row_cur) {
    const int b = blockIdx.x;
    const int t = threadIdx.x;
    const int lane = t & 63, wid = t >> 6;
    const int base = b * SCAN_CHUNK + t * SCAN_PER_THREAD;
    const int lim = min((b + 1) * SCAN_CHUNK, N_NODES);
    int d[SCAN_PER_THREAD];
    int s = 0;
    #pragma unroll
    for (int k = 0; k < SCAN_PER_THREAD; ++k) {
        const int i = base + k;
        d[k] = (i < lim) ? deg[i] : 0;
        s += d[k];
    }
    int x = s;
    #pragma unroll
    for (int off = 1; off < 64; off <<= 1) {
        const int y = __shfl_up(x, off);
        if (lane >= off) x += y;
    }
    __shared__ int wtot[4];
    if (lane == 63) wtot[wid] = x;
    __syncthreads();
    int wo = boff[b];
    for (int k = 0; k < wid; ++k) wo += wtot[k];
    int p = wo + x - s;               // exclusive prefix of this thread's first elem
    #pragma unroll
    for (int k = 0; k < SCAN_PER_THREAD; ++k) {
        const int i = base + k;
        if (i < lim) {
            row_start[i] = p;
            row_cur[i]   = p;
            p += d[k];
        }
    }
}

// ---------------- CSR build: scatter edges ------------------------------------
__global__ void scatter_kernel(const int* __restrict__ edge_user,
                               const int* __restrict__ edge_item,
                               const float* __restrict__ vals,
                               int* __restrict__ row_cur,
                               int* __restrict__ csr_col,
                               float* __restrict__ csr_val) {
    int i = blockIdx.x * blockDim.x + threadIdx.x;
    const int stride = gridDim.x * blockDim.x;
    for (; i < NNZ; i += stride) {
        int row, col;
        if (i < N_EDGES) { row = edge_user[i];            col = N_USERS + edge_item[i]; }
        else { const int e = i - N_EDGES; row = N_USERS + edge_item[e]; col = edge_user[e]; }
        const float v = vals[i];
        const int pos = atomicAdd(&row_cur[row], 1);
        csr_col[pos] = col;
        csr_val[pos] = v;
    }
}

// ---------------- init: cur = acc = concat(user_emb, item_emb) ----------------
__global__ void init_kernel(const float* __restrict__ user_emb,
                            const float* __restrict__ item_emb,
                            float* __restrict__ cur, float* __restrict__ acc) {
    const int total4 = N_NODES * EMB / 4;
    const int user4  = N_USERS * EMB / 4;
    int i = blockIdx.x * blockDim.x + threadIdx.x;
    const int stride = gridDim.x * blockDim.x;
    for (; i < total4; i += stride) {
        float4 v;
        if (i < user4) v = ((const float4*)user_emb)[i];
        else           v = ((const float4*)item_emb)[i - user4];
        ((float4*)cur)[i] = v;
        ((float4*)acc)[i] = v;
    }
}

// ---------------- SpMM (CSR, row-gather): nxt[r] = sum v*cur[c]; acc += nxt ---
__global__ void spmm_csr_kernel(const float* __restrict__ cur,
                                float* __restrict__ nxt,
                                float* __restrict__ acc,
                                const int* __restrict__ row_start,
                                const int* __restrict__ csr_col,
                                const float* __restrict__ csr_val) {
    const int lane = threadIdx.x & 63;
    const int w = blockIdx.x * (blockDim.x >> 6) + (threadIdx.x >> 6);
    if (w >= N_NODES) return;
    const int beg = row_start[w];
    const int end = row_start[w + 1];
    float sx = 0.f, sy = 0.f;
    int j = beg;
    for (; j + 1 < end; j += 2) {
        const int   c0 = csr_col[j];
        const int   c1 = csr_col[j + 1];
        const float v0 = csr_val[j];
        const float v1 = csr_val[j + 1];
        const float2 x0 = ((const float2*)(cur + (size_t)c0 * EMB))[lane];
        const float2 x1 = ((const float2*)(cur + (size_t)c1 * EMB))[lane];
        sx = fmaf(v0, x0.x, sx); sy = fmaf(v0, x0.y, sy);
        sx = fmaf(v1, x1.x, sx); sy = fmaf(v1, x1.y, sy);
    }
    if (j < end) {
        const int   c0 = csr_col[j];
        const float v0 = csr_val[j];
        const float2 x0 = ((const float2*)(cur + (size_t)c0 * EMB))[lane];
        sx = fmaf(v0, x0.x, sx); sy = fmaf(v0, x0.y, sy);
    }
    float2* np = (float2*)(nxt + (size_t)w * EMB) + lane;
    float2* ap = (float2*)(acc + (size_t)w * EMB) + lane;
    np->x = sx; np->y = sy;
    float2 a = *ap;
    a.x += sx; a.y += sy;
    *ap = a;
}

__device__ inline float logsigmoidf(float x) {
    return (x >= 0.f) ? -log1pf(expf(-x)) : (x - log1pf(expf(x)));
}

// ---------------- fused losses (block-reduced atomics) ------------------------
__global__ void loss_kernel(const float* __restrict__ acc,
                            const int* __restrict__ users,
                            const int* __restrict__ pos_items,
                            const int* __restrict__ neg_items,
                            const int* __restrict__ sampled_user,
                            const int* __restrict__ sampled_items,
                            float* __restrict__ sums) {
    const int lane = threadIdx.x & 63;
    const int wid  = threadIdx.x >> 6;            // 0..3
    const int gw   = blockIdx.x * 4 + wid;
    const int nw   = gridDim.x * 4;
    float s_bce = 0.f, s_pred = 0.f, s_plogp = 0.f, s_ul = 0.f;
    for (int p = gw; p < 4 * BATCH; p += nw) {
        int u, it;
        if (p < 2 * BATCH) {
            if (p < BATCH) { u = users[p];          it = pos_items[p]; }
            else           { u = users[p - BATCH];  it = neg_items[p - BATCH]; }
        } else {
            const int q = p - 2 * BATCH;
            u = sampled_user[q]; it = sampled_items[q];
        }
        const float2 a = ((const float2*)(acc + (size_t)u * EMB))[lane];
        const float2 b = ((const float2*)(acc + (size_t)(N_USERS + it) * EMB))[lane];
        float d = a.x * b.x + a.y * b.y;
        #pragma unroll
        for (int off = 32; off > 0; off >>= 1) d += __shfl_down(d, off);
        if (lane == 0) {
            d *= (1.f / 16.f);                  // (acc/4)·(acc/4)
            const float pred = 1.f / (1.f + expf(-d));
            if (p < 2 * BATCH) {
                const float ls  = logsigmoidf(d);
                const float lsn = logsigmoidf(-d);
                s_bce   += (p < BATCH) ? -ls : -lsn;
                s_pred  += pred;
                s_plogp += pred * ls;
            } else {
                s_ul += pred;
            }
        }
    }
    __shared__ float red[4][4];
    if (lane == 0) {
        red[wid][0] = s_bce; red[wid][1] = s_pred;
        red[wid][2] = s_plogp; red[wid][3] = s_ul;
    }
    __syncthreads();
    if (threadIdx.x < 4) {
        const float v = red[0][threadIdx.x] + red[1][threadIdx.x]
                      + red[2][threadIdx.x] + red[3][threadIdx.x];
        atomicAdd(&sums[threadIdx.x], v);
    }
}

// ---------------- finalize ----------------------------------------------------
__global__ void finalize_kernel(const float* __restrict__ sums, float* __restrict__ out) {
    if (threadIdx.x == 0 && blockIdx.x == 0) {
        const float n = 2.f * BATCH;
        const float bce        = sums[0] / n;
        const float pred_avg   = sums[1] / n;
        const float plogp_avg  = sums[2] / n;
        const float predul_avg = sums[3] / n;
        const float info = ALPHA * (-pred_avg * logf(predul_avg)
                                    - (1.f - pred_avg) * logf(1.f - predul_avg))
                         + GAMMA * plogp_avg;
        out[0] = bce;
        out[1] = info;
    }
}

extern "C" void kernel_launch(void* const* d_in, const int* in_sizes, int n_in,
                              void* d_out, int out_size, void* d_ws, size_t ws_size,
                              hipStream_t stream) {
    const float* user_emb      = (const float*)d_in[0];
    const float* item_emb      = (const float*)d_in[1];
    const float* graph_vals    = (const float*)d_in[2];
    const int*   edge_user     = (const int*)d_in[3];
    const int*   edge_item     = (const int*)d_in[4];
    const int*   users         = (const int*)d_in[5];
    const int*   pos_items     = (const int*)d_in[6];
    const int*   neg_items     = (const int*)d_in[7];
    const int*   sampled_user  = (const int*)d_in[8];
    const int*   sampled_items = (const int*)d_in[9];
    float* out = (float*)d_out;

    const size_t embBytes = (size_t)N_NODES * EMB * sizeof(float);  // 71.68 MB
    char* ws = (char*)d_ws;
    size_t off = 0;
    float* bufA = (float*)(ws + off); off += embBytes;
    float* bufB = (float*)(ws + off); off += embBytes;
    float* acc  = (float*)(ws + off); off += embBytes;
    float* sums = (float*)(ws + off); off += 256;  // 4 floats, padded
    int*   deg       = (int*)(ws + off); off += (size_t)N_NODES * 4;
    int*   row_start = (int*)(ws + off); off += (size_t)(N_NODES + 1) * 4 + 252;
    int*   row_cur   = (int*)(ws + off); off += (size_t)N_NODES * 4;
    int*   csr_col   = (int*)(ws + off); off += (size_t)NNZ * 4;
    float* csr_val   = (float*)(ws + off); off += (size_t)NNZ * 4;
    int*   bsum      = (int*)(ws + off); off += (size_t)SCAN_BLOCKS * 4;
    int*   boff      = (int*)(ws + off); off += (size_t)SCAN_BLOCKS * 4;

    hipMemsetAsync(deg, 0, (size_t)N_NODES * 4, stream);
    hipMemsetAsync(sums, 0, 4 * sizeof(float), stream);

    hist_kernel<<<2048, 256, 0, stream>>>(edge_user, edge_item, deg);
    partial_kernel<<<SCAN_BLOCKS, 256, 0, stream>>>(deg, bsum);
    scanb_kernel<<<1, 256, 0, stream>>>(bsum, boff, row_start);
    emit_kernel<<<SCAN_BLOCKS, 256, 0, stream>>>(deg, boff, row_start, row_cur);
    scatter_kernel<<<2048, 256, 0, stream>>>(edge_user, edge_item, graph_vals,
                                             row_cur, csr_col, csr_val);
    init_kernel<<<2048, 256, 0, stream>>>(user_emb, item_emb, bufA, acc);

    float* cur = bufA;
    float* nxt = bufB;
    for (int l = 0; l < N_LAYERS; ++l) {
        spmm_csr_kernel<<<(N_NODES + 3) / 4, 256, 0, stream>>>(cur, nxt, acc,
                                                               row_start, csr_col, csr_val);
        float* t = cur; cur = nxt; nxt = t;
    }

    loss_kernel<<<512, 256, 0, stream>>>(acc, users, pos_items, neg_items,
                                         sampled_user, sampled_items, sums);
    finalize_kernel<<<1, 1, 0, stream>>>(sums, out);
}

// Round 5
// 618.397 us; speedup vs baseline: 17.7855x; 1.2593x over previous
//
#include <hip/hip_runtime.h>
#include <math.h>

#define N_USERS 100000
#define N_ITEMS 40000
#define N_NODES (N_USERS + N_ITEMS)
#define EMB 128
#define EMBW (EMB / 2)            /* 64 uints of packed 2xbf16 per row */
#define BATCH 8192
#define N_EDGES 1000000
#define NNZ (2 * N_EDGES)
#define N_LAYERS 3
#define ALPHA 0.1f
#define GAMMA 0.01f

#define SCAN_BLOCKS 256
#define SCAN_CHUNK ((N_NODES + SCAN_BLOCKS - 1) / SCAN_BLOCKS)   /* 547 */
#define SCAN_PER_THREAD ((SCAN_CHUNK + 255) / 256)               /* 3 */

// ---------- bf16 pack/unpack (RNE) -------------------------------------------
__device__ inline unsigned int f2bf(float x) {
    const unsigned int b = __float_as_uint(x);
    return (b + 0x7FFFu + ((b >> 16) & 1u)) >> 16;
}
__device__ inline float bfl(unsigned int w) { return __uint_as_float(w << 16); }
__device__ inline float bfh(unsigned int w) { return __uint_as_float(w & 0xFFFF0000u); }

// ---------------- CSR build step 1: degree histogram --------------------------
__global__ void hist_kernel(const int* __restrict__ edge_user,
                            const int* __restrict__ edge_item,
                            int* __restrict__ deg) {
    int i = blockIdx.x * blockDim.x + threadIdx.x;
    const int stride = gridDim.x * blockDim.x;
    for (; i < NNZ; i += stride) {
        const int row = (i < N_EDGES) ? edge_user[i]
                                      : N_USERS + edge_item[i - N_EDGES];
        atomicAdd(&deg[row], 1);
    }
}

// ---------------- CSR scan phase 1: per-block chunk sums ----------------------
__global__ void partial_kernel(const int* __restrict__ deg, int* __restrict__ bsum) {
    const int b = blockIdx.x;
    const int t = threadIdx.x;
    const int base = b * SCAN_CHUNK + t * SCAN_PER_THREAD;
    const int lim = min((b + 1) * SCAN_CHUNK, N_NODES);
    int s = 0;
    #pragma unroll
    for (int k = 0; k < SCAN_PER_THREAD; ++k) {
        const int i = base + k;
        if (i < lim) s += deg[i];
    }
    __shared__ int red[4];
    #pragma unroll
    for (int off = 32; off > 0; off >>= 1) s += __shfl_down(s, off);
    const int lane = t & 63, wid = t >> 6;
    if (lane == 0) red[wid] = s;
    __syncthreads();
    if (t == 0) bsum[b] = red[0] + red[1] + red[2] + red[3];
}

// ---------------- CSR scan phase 2: scan 256 block sums -----------------------
__global__ void scanb_kernel(const int* __restrict__ bsum, int* __restrict__ boff,
                             int* __restrict__ row_start) {
    const int t = threadIdx.x;        // 256 threads
    const int lane = t & 63, wid = t >> 6;
    const int v = bsum[t];
    int x = v;
    #pragma unroll
    for (int off = 1; off < 64; off <<= 1) {
        const int y = __shfl_up(x, off);
        if (lane >= off) x += y;
    }
    __shared__ int wtot[4];
    if (lane == 63) wtot[wid] = x;
    __syncthreads();
    int wo = 0;
    for (int k = 0; k < wid; ++k) wo += wtot[k];
    boff[t] = wo + x - v;
    if (t == 255) row_start[N_NODES] = wo + x;   // == NNZ
}

// ---------------- CSR scan phase 3: emit row_start / row_cur ------------------
__global__ void emit_kernel(const int* __restrict__ deg, const int* __restrict__ boff,
                            int* __restrict__ row_start, int* __restrict__ row_cur) {
    const int b = blockIdx.x;
    const int t = threadIdx.x;
    const int lane = t & 63, wid = t >> 6;
    const int base = b * SCAN_CHUNK + t * SCAN_PER_THREAD;
    const int lim = min((b + 1) * SCAN_CHUNK, N_NODES);
    int d[SCAN_PER_THREAD];
    int s = 0;
    #pragma unroll
    for (int k = 0; k < SCAN_PER_THREAD; ++k) {
        const int i = base + k;
        d[k] = (i < lim) ? deg[i] : 0;
        s += d[k];
    }
    int x = s;
    #pragma unroll
    for (int off = 1; off < 64; off <<= 1) {
        const int y = __shfl_up(x, off);
        if (lane >= off) x += y;
    }
    __shared__ int wtot[4];
    if (lane == 63) wtot[wid] = x;
    __syncthreads();
    int wo = boff[b];
    for (int k = 0; k < wid; ++k) wo += wtot[k];
    int p = wo + x - s;
    #pragma unroll
    for (int k = 0; k < SCAN_PER_THREAD; ++k) {
        const int i = base + k;
        if (i < lim) {
            row_start[i] = p;
            row_cur[i]   = p;
            p += d[k];
        }
    }
}

// ---------------- CSR build: scatter edges ------------------------------------
__global__ void scatter_kernel(const int* __restrict__ edge_user,
                               const int* __restrict__ edge_item,
                               const float* __restrict__ vals,
                               int* __restrict__ row_cur,
                               int* __restrict__ csr_col,
                               float* __restrict__ csr_val) {
    int i = blockIdx.x * blockDim.x + threadIdx.x;
    const int stride = gridDim.x * blockDim.x;
    for (; i < NNZ; i += stride) {
        int row, col;
        if (i < N_EDGES) { row = edge_user[i];            col = N_USERS + edge_item[i]; }
        else { const int e = i - N_EDGES; row = N_USERS + edge_item[e]; col = edge_user[e]; }
        const float v = vals[i];
        const int pos = atomicAdd(&row_cur[row], 1);
        csr_col[pos] = col;
        csr_val[pos] = v;
    }
}

// ---------------- init: e0 = bf16(concat(user_emb, item_emb)) -----------------
__global__ void init_kernel(const float* __restrict__ user_emb,
                            const float* __restrict__ item_emb,
                            unsigned int* __restrict__ e0) {
    const int total = N_NODES * EMBW;
    const int u64c  = N_USERS * EMBW;
    int i = blockIdx.x * blockDim.x + threadIdx.x;
    const int stride = gridDim.x * blockDim.x;
    for (; i < total; i += stride) {
        float2 v;
        if (i < u64c) v = ((const float2*)user_emb)[i];
        else          v = ((const float2*)item_emb)[i - u64c];
        e0[i] = f2bf(v.x) | (f2bf(v.y) << 16);
    }
}

// ---------------- SpMM (CSR, bf16 rows): nxt[r] = sum v*cur[c] ----------------
// one 64-lane wave per row; one packed uint (2 bf16) per lane covers EMB=128.
__global__ void spmm_bf16_kernel(const unsigned int* __restrict__ cur,
                                 unsigned int* __restrict__ nxt,
                                 const int* __restrict__ row_start,
                                 const int* __restrict__ csr_col,
                                 const float* __restrict__ csr_val) {
    const int lane = threadIdx.x & 63;
    const int w = blockIdx.x * (blockDim.x >> 6) + (threadIdx.x >> 6);
    if (w >= N_NODES) return;
    const int beg = row_start[w];
    const int end = row_start[w + 1];
    float sx = 0.f, sy = 0.f;
    int j = beg;
    for (; j + 1 < end; j += 2) {
        const int   c0 = csr_col[j];
        const int   c1 = csr_col[j + 1];
        const float v0 = csr_val[j];
        const float v1 = csr_val[j + 1];
        const unsigned int w0 = cur[(size_t)c0 * EMBW + lane];
        const unsigned int w1 = cur[(size_t)c1 * EMBW + lane];
        sx = fmaf(v0, bfl(w0), sx); sy = fmaf(v0, bfh(w0), sy);
        sx = fmaf(v1, bfl(w1), sx); sy = fmaf(v1, bfh(w1), sy);
    }
    if (j < end) {
        const int   c0 = csr_col[j];
        const float v0 = csr_val[j];
        const unsigned int w0 = cur[(size_t)c0 * EMBW + lane];
        sx = fmaf(v0, bfl(w0), sx); sy = fmaf(v0, bfh(w0), sy);
    }
    nxt[(size_t)w * EMBW + lane] = f2bf(sx) | (f2bf(sy) << 16);
}

__device__ inline float logsigmoidf(float x) {
    return (x >= 0.f) ? -log1pf(expf(-x)) : (x - log1pf(expf(x)));
}

// ---------------- fused losses ------------------------------------------------
// acc-row on the fly: e0(fp32 originals) + e1 + e2 + e3 (bf16), dot, /16.
__global__ void loss_kernel(const float* __restrict__ user_emb,
                            const float* __restrict__ item_emb,
                            const unsigned int* __restrict__ e1,
                            const unsigned int* __restrict__ e2,
                            const unsigned int* __restrict__ e3,
                            const int* __restrict__ users,
                            const int* __restrict__ pos_items,
                            const int* __restrict__ neg_items,
                            const int* __restrict__ sampled_user,
                            const int* __restrict__ sampled_items,
                            float* __restrict__ sums) {
    const int lane = threadIdx.x & 63;
    const int wid  = threadIdx.x >> 6;            // 0..3
    const int gw   = blockIdx.x * 4 + wid;
    const int nw   = gridDim.x * 4;
    float s_bce = 0.f, s_pred = 0.f, s_plogp = 0.f, s_ul = 0.f;
    for (int p = gw; p < 4 * BATCH; p += nw) {
        int u, it;
        if (p < 2 * BATCH) {
            if (p < BATCH) { u = users[p];          it = pos_items[p]; }
            else           { u = users[p - BATCH];  it = neg_items[p - BATCH]; }
        } else {
            const int q = p - 2 * BATCH;
            u = sampled_user[q]; it = sampled_items[q];
        }
        const float2 a0 = ((const float2*)(user_emb + (size_t)u * EMB))[lane];
        const size_t ui = (size_t)u * EMBW + lane;
        const unsigned int u1 = e1[ui], u2 = e2[ui], u3 = e3[ui];
        const float ax = a0.x + bfl(u1) + bfl(u2) + bfl(u3);
        const float ay = a0.y + bfh(u1) + bfh(u2) + bfh(u3);
        const float2 b0 = ((const float2*)(item_emb + (size_t)it * EMB))[lane];
        const size_t ii = (size_t)(N_USERS + it) * EMBW + lane;
        const unsigned int i1 = e1[ii], i2 = e2[ii], i3 = e3[ii];
        const float bx = b0.x + bfl(i1) + bfl(i2) + bfl(i3);
        const float by = b0.y + bfh(i1) + bfh(i2) + bfh(i3);
        float d = ax * bx + ay * by;
        #pragma unroll
        for (int off = 32; off > 0; off >>= 1) d += __shfl_down(d, off);
        if (lane == 0) {
            d *= (1.f / 16.f);                  // (acc/4)·(acc/4)
            const float pred = 1.f / (1.f + expf(-d));
            if (p < 2 * BATCH) {
                const float ls  = logsigmoidf(d);
                const float lsn = logsigmoidf(-d);
                s_bce   += (p < BATCH) ? -ls : -lsn;
                s_pred  += pred;
                s_plogp += pred * ls;
            } else {
                s_ul += pred;
            }
        }
    }
    __shared__ float red[4][4];
    if (lane == 0) {
        red[wid][0] = s_bce; red[wid][1] = s_pred;
        red[wid][2] = s_plogp; red[wid][3] = s_ul;
    }
    __syncthreads();
    if (threadIdx.x < 4) {
        const float v = red[0][threadIdx.x] + red[1][threadIdx.x]
                      + red[2][threadIdx.x] + red[3][threadIdx.x];
        atomicAdd(&sums[threadIdx.x], v);
    }
}

// ---------------- finalize ----------------------------------------------------
__global__ void finalize_kernel(const float* __restrict__ sums, float* __restrict__ out) {
    if (threadIdx.x == 0 && blockIdx.x == 0) {
        const float n = 2.f * BATCH;
        const float bce        = sums[0] / n;
        const float pred_avg   = sums[1] / n;
        const float plogp_avg  = sums[2] / n;
        const float predul_avg = sums[3] / n;
        const float info = ALPHA * (-pred_avg * logf(predul_avg)
                                    - (1.f - pred_avg) * logf(1.f - predul_avg))
                         + GAMMA * plogp_avg;
        out[0] = bce;
        out[1] = info;
    }
}

extern "C" void kernel_launch(void* const* d_in, const int* in_sizes, int n_in,
                              void* d_out, int out_size, void* d_ws, size_t ws_size,
                              hipStream_t stream) {
    const float* user_emb      = (const float*)d_in[0];
    const float* item_emb      = (const float*)d_in[1];
    const float* graph_vals    = (const float*)d_in[2];
    const int*   edge_user     = (const int*)d_in[3];
    const int*   edge_item     = (const int*)d_in[4];
    const int*   users         = (const int*)d_in[5];
    const int*   pos_items     = (const int*)d_in[6];
    const int*   neg_items     = (const int*)d_in[7];
    const int*   sampled_user  = (const int*)d_in[8];
    const int*   sampled_items = (const int*)d_in[9];
    float* out = (float*)d_out;

    const size_t ebytes = (size_t)N_NODES * EMBW * sizeof(unsigned int); // 35.84 MB
    char* ws = (char*)d_ws;
    size_t off = 0;
    unsigned int* e0 = (unsigned int*)(ws + off); off += ebytes;
    unsigned int* e1 = (unsigned int*)(ws + off); off += ebytes;
    unsigned int* e2 = (unsigned int*)(ws + off); off += ebytes;
    unsigned int* e3 = (unsigned int*)(ws + off); off += ebytes;
    float* sums = (float*)(ws + off); off += 256;
    int*   deg       = (int*)(ws + off); off += (size_t)N_NODES * 4;
    int*   row_start = (int*)(ws + off); off += (size_t)(N_NODES + 1) * 4 + 252;
    int*   row_cur   = (int*)(ws + off); off += (size_t)N_NODES * 4;
    int*   csr_col   = (int*)(ws + off); off += (size_t)NNZ * 4;
    float* csr_val   = (float*)(ws + off); off += (size_t)NNZ * 4;
    int*   bsum      = (int*)(ws + off); off += (size_t)SCAN_BLOCKS * 4;
    int*   boff      = (int*)(ws + off); off += (size_t)SCAN_BLOCKS * 4;

    hipMemsetAsync(deg, 0, (size_t)N_NODES * 4, stream);
    hipMemsetAsync(sums, 0, 4 * sizeof(float), stream);

    hist_kernel<<<2048, 256, 0, stream>>>(edge_user, edge_item, deg);
    partial_kernel<<<SCAN_BLOCKS, 256, 0, stream>>>(deg, bsum);
    scanb_kernel<<<1, 256, 0, stream>>>(bsum, boff, row_start);
    emit_kernel<<<SCAN_BLOCKS, 256, 0, stream>>>(deg, boff, row_start, row_cur);
    scatter_kernel<<<2048, 256, 0, stream>>>(edge_user, edge_item, graph_vals,
                                             row_cur, csr_col, csr_val);
    init_kernel<<<4096, 256, 0, stream>>>(user_emb, item_emb, e0);

    spmm_bf16_kernel<<<(N_NODES + 3) / 4, 256, 0, stream>>>(e0, e1, row_start,
                                                            csr_col, csr_val);
    spmm_bf16_kernel<<<(N_NODES + 3) / 4, 256, 0, stream>>>(e1, e2, row_start,
                                                            csr_col, csr_val);
    spmm_bf16_kernel<<<(N_NODES + 3) / 4, 256, 0, stream>>>(e2, e3, row_start,
                                                            csr_col, csr_val);

    loss_kernel<<<512, 256, 0, stream>>>(user_emb, item_emb, e1, e2, e3,
                                         users, pos_items, neg_items,
                                         sampled_user, sampled_items, sums);
    finalize_kernel<<<1, 1, 0, stream>>>(sums, out);
}